// Round 4
// baseline (110.006 us; speedup 1.0000x reference)
//
#include <hip/hip_runtime.h>

// AdLIF neuron scan: x [B=32, T=512, D=1024] f32 -> spikes [B, T, D] f32.
// One thread per (b, d) channel.
//
// Round-4 structure: the recurrence loop is LOADS-ONLY (ping-pong 2x32
// register batches). Spikes are packed 1 bit/step into 16 u32 registers and
// expanded to f32 in a separate store phase at the end. This keeps the vmcnt
// FIFO free of stores, so consuming x[t] waits only on genuinely-older
// loads -- ~64 loads stay in flight per wave (512 waves -> ~8 MB machine-wide,
// enough to saturate HBM per Little's law).
//
// FP order matches the JAX reference exactly (mul then add, round-to-nearest,
// NO fma contraction) so spike decisions are bit-stable vs the reference.

#define T_STEPS 512
#define D_DIM   1024

// f32(np.exp(-1/20)), f32(np.exp(-1/200))
#define ALPHA_MEM 0.9512294245007141f
#define ALPHA_ADP 0.9950124791926823f

__device__ __forceinline__ bool adlif_step(float xv, float& v, float& a) {
    // v = alpha_mem * v + x_t
    v = __fadd_rn(__fmul_rn(ALPHA_MEM, v), xv);
    // cur_thr = THRESHOLD + BETA * a  (1.0 + 0.1*a)
    float cur = __fadd_rn(1.0f, __fmul_rn(0.1f, a));
    // s = (v - cur_thr >= THRESHOLD)   -- threshold counts twice, per ref
    float u = __fsub_rn(v, cur);
    bool fired = (u >= 1.0f);
    float s = fired ? 1.0f : 0.0f;
    // a = alpha_adp * a + s
    a = __fadd_rn(__fmul_rn(ALPHA_ADP, a), s);
    // v = v - s * THRESHOLD  (THRESHOLD = 1, exact)
    v = __fsub_rn(v, s);
    return fired;
}

__global__ __launch_bounds__(64) void adlif_kernel(const float* __restrict__ x,
                                                   float* __restrict__ out) {
    const int idx = blockIdx.x * 64 + threadIdx.x;   // 0 .. 32767
    const int b = idx >> 10;                          // / D_DIM
    const int d = idx & (D_DIM - 1);
    const size_t base = (size_t)b * (T_STEPS * D_DIM) + d;
    const float* xp = x + base;
    float* op = out + base;

    float v = 0.0f, a = 0.0f;

    // 512 spike bits, fully static indexing (rule: no runtime-indexed arrays)
    unsigned bits[T_STEPS / 32];
#pragma unroll
    for (int i = 0; i < T_STEPS / 32; ++i) bits[i] = 0u;

    constexpr int U = 32;
    float buf0[U], buf1[U];

#pragma unroll
    for (int i = 0; i < U; ++i) buf0[i] = xp[i * D_DIM];

#pragma unroll
    for (int g = 0; g < T_STEPS / (2 * U); ++g) {     // 8 groups of 64 steps
        const int t0 = g * 2 * U;

        // prefetch group B (t0+32 .. t0+63)
#pragma unroll
        for (int i = 0; i < U; ++i) buf1[i] = xp[(t0 + U + i) * D_DIM];

        // compute group A (loads-only FIFO ahead of us)
#pragma unroll
        for (int i = 0; i < U; ++i) {
            const int t = t0 + i;
            bool f = adlif_step(buf0[i], v, a);
            bits[t >> 5] |= ((unsigned)f) << (t & 31);
        }

        // prefetch group A for next g
        if (g + 1 < T_STEPS / (2 * U)) {
#pragma unroll
            for (int i = 0; i < U; ++i) buf0[i] = xp[(t0 + 2 * U + i) * D_DIM];
        }

        // compute group B
#pragma unroll
        for (int i = 0; i < U; ++i) {
            const int t = t0 + U + i;
            bool f = adlif_step(buf1[i], v, a);
            bits[t >> 5] |= ((unsigned)f) << (t & 31);
        }
    }

    // store phase: expand bits -> f32, non-temporal (written once, never read)
#pragma unroll
    for (int w = 0; w < T_STEPS / 32; ++w) {
        const unsigned wb = bits[w];
#pragma unroll
        for (int k = 0; k < 32; ++k) {
            float s = (float)((wb >> k) & 1u);
            __builtin_nontemporal_store(s, &op[(w * 32 + k) * D_DIM]);
        }
    }
}

extern "C" void kernel_launch(void* const* d_in, const int* in_sizes, int n_in,
                              void* d_out, int out_size, void* d_ws, size_t ws_size,
                              hipStream_t stream) {
    const float* x = (const float*)d_in[0];
    float* out = (float*)d_out;

    const int total = in_sizes[0];            // B*T*D = 16777216
    const int channels = total / T_STEPS;     // B*D  = 32768
    const int blocks = channels / 64;         // 512 blocks of 1 wave each

    adlif_kernel<<<blocks, 64, 0, stream>>>(x, out);
}

// Round 5
// 30.904 us; speedup vs baseline: 3.5596x; 3.5596x over previous
//
#include <hip/hip_runtime.h>

// AdLIF neuron scan: x [B=32, T=512, D=1024] f32 -> spikes [B, T, D] f32.
// One thread per (b, d) channel.
//
// Structure (round 5):
//  - Scan phase is LOADS-ONLY in the vmcnt FIFO: ping-pong 2x32 register
//    batches (r2's shape, which the compiler kept live), spikes packed
//    1 bit/step into one named u32 per 32-step group, ds_write'd to LDS
//    (lgkmcnt, not vmcnt -> load consumption never waits on stores).
//  - Outer loop ROLLED (8 iters) -- r4's full unroll blew the I-cache.
//  - Expand phase: read own packed words from LDS, bits -> f32, NT stores.
//
// FP order matches the JAX reference exactly (mul then add, round-to-nearest,
// NO fma contraction) so spike decisions are bit-stable vs the reference.

#define T_STEPS 512
#define D_DIM   1024

// f32(np.exp(-1/20)), f32(np.exp(-1/200))
#define ALPHA_MEM 0.9512294245007141f
#define ALPHA_ADP 0.9950124791926823f

__device__ __forceinline__ bool adlif_step(float xv, float& v, float& a) {
    // v = alpha_mem * v + x_t
    v = __fadd_rn(__fmul_rn(ALPHA_MEM, v), xv);
    // cur_thr = THRESHOLD + BETA * a  (1.0 + 0.1*a)
    float cur = __fadd_rn(1.0f, __fmul_rn(0.1f, a));
    // s = (v - cur_thr >= THRESHOLD)   -- threshold counts twice, per ref
    float u = __fsub_rn(v, cur);
    bool fired = (u >= 1.0f);
    float s = fired ? 1.0f : 0.0f;
    // a = alpha_adp * a + s
    a = __fadd_rn(__fmul_rn(ALPHA_ADP, a), s);
    // v = v - s * THRESHOLD  (THRESHOLD = 1, exact)
    v = __fsub_rn(v, s);
    return fired;
}

__global__ __launch_bounds__(64) void adlif_kernel(const float* __restrict__ x,
                                                   float* __restrict__ out) {
    // 16 packed words per thread, padded to 17 to kill LDS bank conflicts
    __shared__ unsigned sbits[64 * 17];

    const int tid = threadIdx.x;
    const int idx = blockIdx.x * 64 + tid;            // 0 .. 32767
    const int b = idx >> 10;                          // / D_DIM
    const int d = idx & (D_DIM - 1);
    const size_t base = (size_t)b * (T_STEPS * D_DIM) + d;
    const float* xp = x + base;
    float* op = out + base;

    float v = 0.0f, a = 0.0f;

    constexpr int U = 32;
    float buf0[U], buf1[U];

#pragma unroll
    for (int i = 0; i < U; ++i) buf0[i] = xp[i * D_DIM];

    // ---- scan phase: 8 rolled iterations x (2 groups of 32 steps) ----
    for (int it = 0; it < T_STEPS / (2 * U); ++it) {
        const int t0 = it * 2 * U;

        // prefetch group B (t0+32 .. t0+63)
#pragma unroll
        for (int i = 0; i < U; ++i) buf1[i] = xp[(t0 + U + i) * D_DIM];

        // compute group A -> one packed word
        unsigned wA = 0u;
#pragma unroll
        for (int i = 0; i < U; ++i) {
            bool f = adlif_step(buf0[i], v, a);
            wA |= ((unsigned)f) << i;
        }
        sbits[tid * 17 + it * 2] = wA;

        // prefetch group A for next iteration
        if (it + 1 < T_STEPS / (2 * U)) {
#pragma unroll
            for (int i = 0; i < U; ++i) buf0[i] = xp[(t0 + 2 * U + i) * D_DIM];
        }

        // compute group B -> one packed word
        unsigned wB = 0u;
#pragma unroll
        for (int i = 0; i < U; ++i) {
            bool f = adlif_step(buf1[i], v, a);
            wB |= ((unsigned)f) << i;
        }
        sbits[tid * 17 + it * 2 + 1] = wB;
    }

    // ---- expand phase: own words only (no barrier), bits -> f32, NT store ----
    for (int w = 0; w < T_STEPS / 32; ++w) {
        const unsigned wb = sbits[tid * 17 + w];
#pragma unroll
        for (int k = 0; k < 32; ++k) {
            float s = (float)((wb >> k) & 1u);
            __builtin_nontemporal_store(s, &op[(size_t)(w * 32 + k) * D_DIM]);
        }
    }
}

extern "C" void kernel_launch(void* const* d_in, const int* in_sizes, int n_in,
                              void* d_out, int out_size, void* d_ws, size_t ws_size,
                              hipStream_t stream) {
    const float* x = (const float*)d_in[0];
    float* out = (float*)d_out;

    const int total = in_sizes[0];            // B*T*D = 16777216
    const int channels = total / T_STEPS;     // B*D  = 32768
    const int blocks = channels / 64;         // 512 blocks of 1 wave each

    adlif_kernel<<<blocks, 64, 0, stream>>>(x, out);
}